// Round 1
// baseline (183.761 us; speedup 1.0000x reference)
//
#include <hip/hip_runtime.h>
#include <hip/hip_bf16.h>
#include <math.h>
#include <stdint.h>

#define BB 4
#define TT 1024
#define EE 1024
#define HH 16
#define SS 64

typedef unsigned short ushort_t;
typedef __attribute__((ext_vector_type(8))) short bf16x8;
typedef __attribute__((ext_vector_type(8))) unsigned short u16x8;
typedef __attribute__((ext_vector_type(4))) unsigned short u16x4;
typedef __attribute__((ext_vector_type(4))) float f32x4;

__device__ __forceinline__ float b2f(ushort_t u) {
    union { float f; uint32_t i; } c;
    c.i = ((uint32_t)u) << 16;
    return c.f;
}
__device__ __forceinline__ ushort_t f2b(float f) {
    __hip_bfloat16 h = __float2bfloat16(f);
    return *(ushort_t*)&h;
}

// ---------------------------------------------------------------------------
// Kernel 0: fused fp32 -> bf16 converter, 4 elems/thread (Er then Wo)
// ---------------------------------------------------------------------------
__global__ __launch_bounds__(256) void cvt2_kernel(
    const float* __restrict__ a, ushort_t* __restrict__ da, int na,
    const float* __restrict__ b, ushort_t* __restrict__ db, int nb)
{
    const int i4 = (blockIdx.x * 256 + threadIdx.x) * 4;
    if (i4 < na) {
        const float4 xv = *(const float4*)&a[i4];
        u16x4 o4 = { f2b(xv.x), f2b(xv.y), f2b(xv.z), f2b(xv.w) };
        *(u16x4*)&da[i4] = o4;
    } else {
        const int j4 = i4 - na;
        if (j4 < nb) {
            const float4 xv = *(const float4*)&b[j4];
            u16x4 o4 = { f2b(xv.x), f2b(xv.y), f2b(xv.z), f2b(xv.w) };
            *(u16x4*)&db[j4] = o4;
        }
    }
}

// ---------------------------------------------------------------------------
// Kernel 1: MFMA q/k/v projection + fused vmean accumulation. (unchanged)
// ---------------------------------------------------------------------------
__global__ __launch_bounds__(256) void qkv_kernel(
    const float* __restrict__ x, const float* __restrict__ Wq,
    const float* __restrict__ Wk, const float* __restrict__ Wv,
    ushort_t* __restrict__ q, ushort_t* __restrict__ k, ushort_t* __restrict__ v,
    float* __restrict__ vmean)
{
    __shared__ __align__(16) ushort_t Xs[128][72];
    __shared__ __align__(16) ushort_t Wl[3][64][72];

    const int tid  = threadIdx.x;
    const int lane = tid & 63;
    const int w    = tid >> 6;
    const int m    = lane & 15;
    const int qd   = lane >> 4;
    const int n0   = blockIdx.x * 128;
    const int hh   = blockIdx.y;
    const int bb   = n0 >> 10;

#pragma unroll
    for (int l = 0; l < 8; l++) {
        const int idx = tid + 256 * l;
        const int row = idx >> 4;
        const int c4  = idx & 15;
        const float4 xv = *(const float4*)&x[(size_t)(n0 + row) * 1024 + hh * 64 + c4 * 4];
        u16x4 o4 = { f2b(xv.x), f2b(xv.y), f2b(xv.z), f2b(xv.w) };
        *(u16x4*)&Xs[row][c4 * 4] = o4;
    }
#pragma unroll
    for (int l = 0; l < 12; l++) {
        const int idx = tid + 256 * l;
        const int mo  = idx >> 10;
        const int r   = (idx >> 4) & 63;
        const int c4  = idx & 15;
        const float* W = (mo == 0) ? Wq : (mo == 1) ? Wk : Wv;
        const float4 wv = *(const float4*)&W[r * 64 + c4 * 4];
        u16x4 o4 = { f2b(wv.x), f2b(wv.y), f2b(wv.z), f2b(wv.w) };
        *(u16x4*)&Wl[mo][r][c4 * 4] = o4;
    }
    __syncthreads();

    f32x4 acc[2][3][4];
#pragma unroll
    for (int rt = 0; rt < 2; rt++)
#pragma unroll
        for (int mo = 0; mo < 3; mo++)
#pragma unroll
            for (int ct = 0; ct < 4; ct++) acc[rt][mo][ct] = {0.f, 0.f, 0.f, 0.f};

#pragma unroll
    for (int ks = 0; ks < 2; ks++) {
        bf16x8 af[2];
#pragma unroll
        for (int rt = 0; rt < 2; rt++)
            af[rt] = *(const bf16x8*)&Xs[32 * w + 16 * rt + m][ks * 32 + qd * 8];
#pragma unroll
        for (int mo = 0; mo < 3; mo++)
#pragma unroll
            for (int ct = 0; ct < 4; ct++) {
                bf16x8 bw = *(const bf16x8*)&Wl[mo][ct * 16 + m][ks * 32 + qd * 8];
#pragma unroll
                for (int rt = 0; rt < 2; rt++)
                    acc[rt][mo][ct] = __builtin_amdgcn_mfma_f32_16x16x32_bf16(
                        af[rt], bw, acc[rt][mo][ct], 0, 0, 0);
            }
    }

    const size_t obase = ((size_t)bb * HH + hh) * TT;
#pragma unroll
    for (int mo = 0; mo < 3; mo++) {
        ushort_t* dst = (mo == 0) ? q : (mo == 1) ? k : v;
        const float sc = (mo == 1) ? 0.03125f : 1.0f;
#pragma unroll
        for (int rt = 0; rt < 2; rt++)
#pragma unroll
            for (int reg = 0; reg < 4; reg++) {
                const int t = (n0 & 1023) + 32 * w + 16 * rt + qd * 4 + reg;
#pragma unroll
                for (int ct = 0; ct < 4; ct++)
                    dst[(obase + t) * SS + ct * 16 + m] = f2b(acc[rt][mo][ct][reg] * sc);
            }
    }

#pragma unroll
    for (int ct = 0; ct < 4; ct++) {
        float s = 0.f;
#pragma unroll
        for (int rt = 0; rt < 2; rt++)
#pragma unroll
            for (int reg = 0; reg < 4; reg++) s += acc[rt][2][ct][reg];
        s += __shfl_xor(s, 16);
        s += __shfl_xor(s, 32);
        if (qd == 0)
            atomicAdd(&vmean[(bb * HH + hh) * SS + ct * 16 + m], s);
    }
}

// ---------------------------------------------------------------------------
// Kernel 3: MFMA bf16 flash attention, SPLIT-J load-balanced version.
// Softmax here has no running max (exp of bounded scores, verified R11
// structure), so partial (o, lsum) over disjoint j-ranges combine by pure
// addition: each block handles a chunk of <=8 j-steps of one i-tile and
// atomically accumulates fp32 partials into Ows/Lws (must be pre-zeroed).
// Chunking: tile y has 2y+2 steps -> ceil((2y+2)/8) chunks, evenly split.
// 40 chunk-slots per bh -> grid (64, 40) = 2560 near-uniform blocks
// (2..8 iters each) instead of 1024 blocks of 2..32 iters.
// ---------------------------------------------------------------------------
__global__ __launch_bounds__(256) void attn_kernel(
    const ushort_t* __restrict__ q, const ushort_t* __restrict__ k,
    const ushort_t* __restrict__ v, const ushort_t* __restrict__ er,
    float* __restrict__ Ows, float* __restrict__ Lws)
{
    __shared__ __align__(16) ushort_t Qs[64][72];
    __shared__ __align__(16) ushort_t Ks[32][72];
    __shared__ __align__(16) ushort_t Vt4[4][64][8];
    __shared__ __align__(16) ushort_t Es[96][72];
    __shared__ __align__(16) ushort_t Ps[4][16][40];

    const int tid  = threadIdx.x;
    const int lane = tid & 63;
    const int w    = tid >> 6;
    const int m    = lane & 15;
    const int qd   = lane >> 4;
    const int bh   = blockIdx.x;
    const int hh   = bh & 15;

    // ---- chunk-slot -> (i-tile y, chunk c of nc) mapping (scalar) ----
    const int slot = blockIdx.y;
    int y, c, nc;
    if (slot < 4)       { y = slot;                c = 0;              nc = 1; }
    else if (slot < 12) { y = 4 + ((slot - 4) >> 1);  c = (slot - 4) & 1;  nc = 2; }
    else if (slot < 24) { y = 8 + (slot - 12) / 3;    c = (slot - 12) % 3; nc = 3; }
    else                { y = 12 + ((slot - 24) >> 2); c = (slot - 24) & 3; nc = 4; }
    const int i0    = y * 64;
    const int NS    = 2 * y + 2;                    // total 32-wide j-steps
    const int qs    = NS / nc, rs = NS % nc;
    const int steps = qs + (c < rs ? 1 : 0);
    const int start = c * qs + (c < rs ? c : rs);
    const int j0s   = 32 * start;

    const ushort_t* qb = q + (size_t)bh * TT * SS;
    const ushort_t* kb = k + (size_t)bh * TT * SS;
    const ushort_t* vb = v + (size_t)bh * TT * SS;
    const ushort_t* eb = er + (size_t)hh * TT * SS;
    const int l0 = 960 - i0;

    for (int cc = tid; cc < 512; cc += 256) {
        int row = cc >> 3, sub = cc & 7;
        *(uint4*)&Qs[row][sub * 8] = ((const uint4*)qb)[(size_t)(i0 + row) * 8 + sub];
    }
    // initial Er window: absolute positions x in [j0s, j0s+64) at slot x%96
    for (int cc = tid; cc < 512; cc += 256) {
        int row = cc >> 3, sub = cc & 7;
        int x = j0s + row;
        int l = l0 + x;
        uint4 val = {0u, 0u, 0u, 0u};
        if (l <= 1023) val = ((const uint4*)eb)[(size_t)l * 8 + sub];
        *(uint4*)&Es[x % 96][sub * 8] = val;
    }

    const int krow = tid >> 3, ksub = tid & 7;
    const int vd   = tid & 63, vjh = tid >> 6;
    uint4 kreg, ereg;
    u16x8 vreg;

    {
        kreg = ((const uint4*)kb)[(size_t)(j0s + krow) * 8 + ksub];
#pragma unroll
        for (int jj = 0; jj < 8; jj++)
            vreg[jj] = vb[(size_t)(j0s + vjh * 8 + jj) * SS + vd];
        const int l = l0 + j0s + 64 + krow;
        ereg = (uint4){0u, 0u, 0u, 0u};
        if (l <= 1023) ereg = ((const uint4*)eb)[(size_t)l * 8 + ksub];
    }
    __syncthreads();

    bf16x8 aq[2];
#pragma unroll
    for (int ks = 0; ks < 2; ks++)
        aq[ks] = *(const bf16x8*)&Qs[16 * w + m][ks * 32 + qd * 8];

    f32x4 o[4];
#pragma unroll
    for (int vt = 0; vt < 4; vt++) o[vt] = {0.f, 0.f, 0.f, 0.f};
    float lsum[4] = {0.f, 0.f, 0.f, 0.f};

    const int ow = 48 - 16 * w;
    const int srcbase = lane & 48;

    int j0 = j0s;
    for (int t = 0; t < steps; ++t, j0 += 32) {
        *(uint4*)&Ks[krow][ksub * 8] = kreg;
        *(u16x8*)&Vt4[vjh][vd][0] = vreg;
        {
            const int sslot = (64 + j0) % 96 + krow;
            *(uint4*)&Es[sslot][ksub * 8] = ereg;
        }
        __syncthreads();

        if (t + 1 < steps) {
            const int jn = j0 + 32;
            kreg = ((const uint4*)kb)[(size_t)(jn + krow) * 8 + ksub];
#pragma unroll
            for (int jj = 0; jj < 8; jj++)
                vreg[jj] = vb[(size_t)(jn + vjh * 8 + jj) * SS + vd];
            const int l = l0 + 64 + jn + krow;
            ereg = (uint4){0u, 0u, 0u, 0u};
            if (l <= 1023) ereg = ((const uint4*)eb)[(size_t)l * 8 + ksub];
        }

        f32x4 s[2];
#pragma unroll
        for (int ct = 0; ct < 2; ct++) {
            s[ct] = {0.f, 0.f, 0.f, 0.f};
#pragma unroll
            for (int ks = 0; ks < 2; ks++) {
                bf16x8 bk = *(const bf16x8*)&Ks[16 * ct + m][ks * 32 + qd * 8];
                s[ct] = __builtin_amdgcn_mfma_f32_16x16x32_bf16(aq[ks], bk, s[ct], 0, 0, 0);
            }
        }
        f32x4 r[3];
#pragma unroll
        for (int rt = 0; rt < 3; rt++) {
            const int row0 = (ow + 16 * rt + j0) % 96;
            r[rt] = {0.f, 0.f, 0.f, 0.f};
#pragma unroll
            for (int ks = 0; ks < 2; ks++) {
                bf16x8 be = *(const bf16x8*)&Es[row0 + m][ks * 32 + qd * 8];
                r[rt] = __builtin_amdgcn_mfma_f32_16x16x32_bf16(aq[ks], be, r[rt], 0, 0, 0);
            }
        }

#pragma unroll
        for (int reg = 0; reg < 4; reg++) {
            const int r_ = qd * 4 + reg;
            const int i_ = i0 + 16 * w + r_;
            const int base = 15 - r_ + m;
            const int src  = srcbase | (base & 15);
            const float c0 = __shfl(r[0][reg], src);
            const float c1 = __shfl(r[1][reg], src);
            const float c2 = __shfl(r[2][reg], src);
            const float e0 = (base < 16) ? c0 : c1;
            const float e1 = (base < 16) ? c1 : c2;
            const float v0 = s[0][reg] + e0;
            const float v1 = s[1][reg] + e1;
            const float p0 = (j0 + m      > i_) ? 0.f : __expf(v0);
            const float p1 = (j0 + m + 16 > i_) ? 0.f : __expf(v1);
            lsum[reg] += p0 + p1;
            Ps[w][r_][m]      = f2b(p0);
            Ps[w][r_][m + 16] = f2b(p1);
        }

        bf16x8 pa = *(const bf16x8*)&Ps[w][m][qd * 8];
#pragma unroll
        for (int vt = 0; vt < 4; vt++) {
            bf16x8 bv = *(const bf16x8*)&Vt4[qd][16 * vt + m][0];
            o[vt] = __builtin_amdgcn_mfma_f32_16x16x32_bf16(pa, bv, o[vt], 0, 0, 0);
        }
        __syncthreads();
    }

    // ---- epilogue: accumulate fp32 partials (additive combine, no max) ----
#pragma unroll
    for (int reg = 0; reg < 4; reg++) {
        float l = lsum[reg];
#pragma unroll
        for (int off = 1; off < 16; off <<= 1) l += __shfl_xor(l, off);
        const int r_ = qd * 4 + reg;
        const int i_ = i0 + 16 * w + r_;
        if (m == 0) atomicAdd(&Lws[bh * TT + i_], l);
        const size_t obase = ((size_t)bh * TT + i_) * SS;
#pragma unroll
        for (int vt = 0; vt < 4; vt++)
            atomicAdd(&Ows[obase + 16 * vt + m], o[vt][reg]);
    }
}

// ---------------------------------------------------------------------------
// Kernel 3b: combine partials -> normalized bf16 attn matrix (permuted
// layout expected by outproj), with mask->vmean substitution.
// One float4 per thread over BB*HH*TT*SS elements.
// ---------------------------------------------------------------------------
__global__ __launch_bounds__(256) void combine_kernel(
    const float* __restrict__ Ows, const float* __restrict__ Lws,
    const int* __restrict__ mask, const float* __restrict__ vmean,
    ushort_t* __restrict__ attn)
{
    const int e0  = (blockIdx.x * 256 + threadIdx.x) * 4;
    const int d0  = e0 & 63;
    const int row = e0 >> 6;          // bh*1024 + i
    const int i   = row & 1023;
    const int bh  = row >> 10;
    const int bb  = bh >> 4;
    const int hh  = bh & 15;

    float4 res;
    if (mask[bb * TT + i] == 0) {
        const float4 vm = *(const float4*)&vmean[bh * SS + d0];
        res.x = vm.x * (1.0f / 1024.0f);
        res.y = vm.y * (1.0f / 1024.0f);
        res.z = vm.z * (1.0f / 1024.0f);
        res.w = vm.w * (1.0f / 1024.0f);
    } else {
        const float4 ov = *(const float4*)&Ows[e0];
        const float inv = 1.0f / Lws[row];
        res.x = ov.x * inv;
        res.y = ov.y * inv;
        res.z = ov.z * inv;
        res.w = ov.w * inv;
    }
    u16x4 o4 = { f2b(res.x), f2b(res.y), f2b(res.z), f2b(res.w) };
    const size_t widx = ((size_t)bb * TT + hh * 64 + (i >> 4)) * EE + (i & 15) * 64 + d0;
    *(u16x4*)&attn[widx] = o4;
}

// ---------------------------------------------------------------------------
// Kernel 4: MFMA bf16 GEMM  out = M @ Wo16^T + bo  (unchanged)
// ---------------------------------------------------------------------------
__global__ __launch_bounds__(256) void outproj_kernel(
    const ushort_t* __restrict__ A, const ushort_t* __restrict__ Wo,
    const float* __restrict__ bo, float* __restrict__ out)
{
    __shared__ __align__(16) ushort_t As[128][36];
    __shared__ __align__(16) ushort_t Bs[128][36];

    const int tid  = threadIdx.x;
    const int lane = tid & 63;
    const int w    = tid >> 6;
    const int m    = lane & 15;
    const int qd   = lane >> 4;
    const int wrow = (w & 1) * 64;
    const int wcol = (w >> 1) * 64;
    const int o0   = blockIdx.x * 128;
    const int n0   = blockIdx.y * 128;

    f32x4 acc[4][4];
#pragma unroll
    for (int rt = 0; rt < 4; rt++)
#pragma unroll
        for (int ct = 0; ct < 4; ct++) acc[rt][ct] = {0.f, 0.f, 0.f, 0.f};

    for (int k0 = 0; k0 < 1024; k0 += 32) {
        __syncthreads();
#pragma unroll
        for (int l = 0; l < 2; l++) {
            const int idx = tid + 256 * l;
            const int row = idx >> 2;
            const int sub = idx & 3;
            *(uint4*)&As[row][sub * 8] =
                *(const uint4*)&A[(size_t)(n0 + row) * 1024 + k0 + sub * 8];
            *(uint4*)&Bs[row][sub * 8] =
                *(const uint4*)&Wo[(size_t)(o0 + row) * 1024 + k0 + sub * 8];
        }
        __syncthreads();

        bf16x8 af[4], bf[4];
#pragma unroll
        for (int rt = 0; rt < 4; rt++)
            af[rt] = *(const bf16x8*)&As[wrow + rt * 16 + m][qd * 8];
#pragma unroll
        for (int ct = 0; ct < 4; ct++)
            bf[ct] = *(const bf16x8*)&Bs[wcol + ct * 16 + m][qd * 8];
#pragma unroll
        for (int rt = 0; rt < 4; rt++)
#pragma unroll
            for (int ct = 0; ct < 4; ct++)
                acc[rt][ct] = __builtin_amdgcn_mfma_f32_16x16x32_bf16(
                    af[rt], bf[ct], acc[rt][ct], 0, 0, 0);
    }

#pragma unroll
    for (int rt = 0; rt < 4; rt++) {
#pragma unroll
        for (int ct = 0; ct < 4; ct++) {
            const int oc = o0 + wcol + ct * 16 + m;
            const float bias = bo[oc];
#pragma unroll
            for (int reg = 0; reg < 4; reg++) {
                const int n = n0 + wrow + rt * 16 + qd * 4 + reg;
                out[(size_t)n * EE + oc] = acc[rt][ct][reg] + bias;
            }
        }
    }
}

// ---------------------------------------------------------------------------
// Launcher.  ws (ushort): q16|k16|v16 (4M each) | er16 (1M) | wo16 (1M)
//            | M16 (4M) | vmean f32 (4096) | Ows f32 (4.19M) | Lws f32 (64K)
// ---------------------------------------------------------------------------
extern "C" void kernel_launch(void* const* d_in, const int* in_sizes, int n_in,
                              void* d_out, int out_size, void* d_ws, size_t ws_size,
                              hipStream_t stream)
{
    const float* x    = (const float*)d_in[0];
    const int*   mask = (const int*)d_in[1];
    const float* Wq   = (const float*)d_in[2];
    const float* Wk   = (const float*)d_in[3];
    const float* Wv   = (const float*)d_in[4];
    const float* Er   = (const float*)d_in[5];
    const float* Wo   = (const float*)d_in[6];
    const float* bo   = (const float*)d_in[7];
    float* out = (float*)d_out;

    const size_t QKV = (size_t)BB * HH * TT * SS;
    const int    nEr = HH * TT * SS;
    const int    nWo = EE * EE;
    ushort_t* q16   = (ushort_t*)d_ws;
    ushort_t* k16   = q16 + QKV;
    ushort_t* v16   = k16 + QKV;
    ushort_t* er16  = v16 + QKV;
    ushort_t* wo16  = er16 + nEr;
    ushort_t* M16   = wo16 + nWo;
    float*    vmean = (float*)(M16 + QKV);
    float*    Ows   = vmean + BB * HH * SS;
    float*    Lws   = Ows + QKV;

    // zero vmean + Ows + Lws in one contiguous memset
    hipMemsetAsync(vmean, 0, (BB * HH * SS + QKV + BB * HH * TT) * sizeof(float), stream);
    cvt2_kernel<<<dim3((nEr + nWo) / 1024), 256, 0, stream>>>(Er, er16, nEr, Wo, wo16, nWo);
    qkv_kernel<<<dim3(BB * TT / 128, HH), 256, 0, stream>>>(x, Wq, Wk, Wv, q16, k16, v16, vmean);
    attn_kernel<<<dim3(BB * HH, 40), 256, 0, stream>>>(q16, k16, v16, er16, Ows, Lws);
    combine_kernel<<<dim3(QKV / 1024), 256, 0, stream>>>(Ows, Lws, mask, vmean, M16);
    outproj_kernel<<<dim3(EE / 128, BB * TT / 128), 256, 0, stream>>>(M16, wo16, bo, out);
}